// Round 8
// baseline (424.573 us; speedup 1.0000x reference)
//
#include <hip/hip_runtime.h>
#include <hip/hip_bf16.h>

using bf16 = __hip_bfloat16;
using u16  = unsigned short;
typedef __attribute__((ext_vector_type(8))) short s16x8;
typedef __attribute__((ext_vector_type(4))) float f32x4;

__device__ __forceinline__ float b2f(u16 u){
  union{unsigned u; float f;} c; c.u = ((unsigned)u)<<16; return c.f;
}
__device__ __forceinline__ u16 f2b(float f){
  __hip_bfloat16 h = __float2bfloat16(f);
  return *reinterpret_cast<u16*>(&h);
}

#define GLDS16(g, l_) __builtin_amdgcn_global_load_lds( \
    (const __attribute__((address_space(1))) unsigned int*)(g), \
    (__attribute__((address_space(3))) unsigned int*)(l_), 16, 0, 0)

// ---------------- GroupNorm: x[4,4096,512] fp32 -> h bf16, 32 groups of 16 ch ------
__global__ __launch_bounds__(512) void gn_kernel(const float* __restrict__ x,
    const float* __restrict__ gamma, const float* __restrict__ beta,
    bf16* __restrict__ h)
{
  const int b = blockIdx.x >> 5, g = blockIdx.x & 31;
  const int t = threadIdx.x;
  const size_t base = (size_t)b*4096*512 + (size_t)g*16;
  float sum = 0.f, sq = 0.f;
  for (int i = 0; i < 8; i++){
    const float* p = x + base + (size_t)(i*512 + t)*512;
    #pragma unroll
    for (int j = 0; j < 4; j++){
      f32x4 v = *(const f32x4*)(p + j*4);
      #pragma unroll
      for (int e = 0; e < 4; e++){ sum += v[e]; sq += v[e]*v[e]; }
    }
  }
  __shared__ float red[16];
  for (int o = 32; o > 0; o >>= 1){ sum += __shfl_xor(sum, o); sq += __shfl_xor(sq, o); }
  const int w = t >> 6, l = t & 63;
  if (l == 0){ red[w] = sum; red[8 + w] = sq; }
  __syncthreads();
  if (t == 0){
    float a = 0.f, bb = 0.f;
    for (int i = 0; i < 8; i++){ a += red[i]; bb += red[8 + i]; }
    red[0] = a; red[8] = bb;
  }
  __syncthreads();
  const float inv_n = 1.f/65536.f;
  const float mean = red[0]*inv_n;
  const float var  = red[8]*inv_n - mean*mean;
  const float rstd = rsqrtf(var + 1e-6f);
  float ga[16], be[16];
  #pragma unroll
  for (int j = 0; j < 16; j++){
    ga[j] = gamma[g*16 + j];
    be[j] = beta [g*16 + j];
  }
  u16* hp = (u16*)h;
  for (int i = 0; i < 8; i++){
    const float* p = x + base + (size_t)(i*512 + t)*512;
    u16* q = hp + base + (size_t)(i*512 + t)*512;
    s16x8 o0, o1;
    #pragma unroll
    for (int j = 0; j < 4; j++){
      f32x4 v = *(const f32x4*)(p + j*4);
      #pragma unroll
      for (int e = 0; e < 4; e++){
        int c = j*4 + e;
        u16 r = f2b((v[e] - mean)*rstd*ga[c] + be[c]);
        if (c < 8) o0[c] = (short)r; else o1[c - 8] = (short)r;
      }
    }
    *(s16x8*)q = o0; *(s16x8*)(q + 8) = o1;
  }
}

// ---------------- Weight transpose: 4x [512,512] fp32 -> bf16 transposed -----------
struct W4 { const float* p[4]; };
__global__ __launch_bounds__(256) void transpose_w4(W4 srcs, bf16* __restrict__ dst)
{
  __shared__ float tile[64][65];
  const float* in = srcs.p[blockIdx.z];
  u16* out = (u16*)dst + (size_t)blockIdx.z*512*512;
  const int tr = blockIdx.y*64, tc = blockIdx.x*64;
  const int t = threadIdx.x;
  #pragma unroll
  for (int i = 0; i < 16; i++){
    int idx = i*256 + t, r = idx >> 6, c = idx & 63;
    tile[r][c] = in[(size_t)(tr + r)*512 + tc + c];
  }
  __syncthreads();
  #pragma unroll
  for (int i = 0; i < 16; i++){
    int idx = i*256 + t, r = idx >> 6, c = idx & 63;
    out[(size_t)(tc + r)*512 + tr + c] = f2b(tile[c][r]);
  }
}

// ---------------- V transpose: qkv[:,1024:1536] (bf16, ld 1536) -> vT[b][512][4096]
__global__ __launch_bounds__(256) void transpose_v(const u16* __restrict__ qkv,
    bf16* __restrict__ vT)
{
  __shared__ u16 tile[64][72];
  const u16* in = qkv + 1024 + (size_t)blockIdx.z*4096*1536;
  u16* out = (u16*)vT + (size_t)blockIdx.z*512*4096;
  const int tr = blockIdx.y*64, tc = blockIdx.x*64;   // tr: n rows, tc: c cols
  const int t = threadIdx.x;
  #pragma unroll
  for (int i = 0; i < 16; i++){
    int idx = i*256 + t, r = idx >> 6, c = idx & 63;
    tile[r][c] = in[(size_t)(tr + r)*1536 + tc + c];
  }
  __syncthreads();
  #pragma unroll
  for (int i = 0; i < 16; i++){
    int idx = i*256 + t, r = idx >> 6, c = idx & 63;
    out[(size_t)(tc + r)*4096 + tr + c] = tile[c][r];
  }
}

// ---------------- 128x128 GEMM (BT form), used for out-proj + fallback -------------
// EPI bits: 1 = +b0[col], 2 = *scale, 4 = +res[row*ldc+col] (fp32), 8 = QKV 3-way bias.
template<int EPI, typename OutT>
__global__ __launch_bounds__(256) void gemm_bt(
    const u16* __restrict__ A, int lda, long sA,
    const u16* __restrict__ Bt, int ldb, long sB,
    OutT* __restrict__ Cmat, int ldc, long sC,
    int K, float scale,
    const float* __restrict__ b0, const float* __restrict__ b1,
    const float* __restrict__ b2, const float* __restrict__ res)
{
  __shared__ u16 As[128*64];
  __shared__ u16 Bs[128*64];
  const int t = threadIdx.x, l = t & 63, w = t >> 6;
  const int wr = w >> 1, wc = w & 1;
  int bx = blockIdx.x, by = blockIdx.y;
  {
    const int gx = gridDim.x, nb = gx * gridDim.y;
    if ((nb & 7) == 0){
      int lin = by*gx + bx;
      int s = (lin & 7)*(nb >> 3) + (lin >> 3);
      bx = s % gx; by = s / gx;
    }
  }
  const int m0 = by * 128, n0 = bx * 128;
  const u16* Au  = A  + (size_t)blockIdx.z * sA;
  const u16* Btu = Bt + (size_t)blockIdx.z * sB;

  f32x4 acc[4][4];
  #pragma unroll
  for (int m = 0; m < 4; m++)
    #pragma unroll
    for (int n = 0; n < 4; n++) acc[m][n] = (f32x4){0.f,0.f,0.f,0.f};

  const int srow = l >> 3;
  const int scol = ((l & 7) ^ srow) * 8;
  const int xorv = (l & 7) << 4;
  const int nkt = K >> 6;
  for (int kt = 0; kt < nkt; ++kt){
    const int k0 = kt << 6;
    #pragma unroll
    for (int j = 0; j < 4; j++){
      const int chunk = w*4 + j;
      const int row = chunk*8 + srow;
      GLDS16(Au  + (size_t)(m0 + row)*lda + k0 + scol, &As[chunk*512]);
      GLDS16(Btu + (size_t)(n0 + row)*ldb + k0 + scol, &Bs[chunk*512]);
    }
    __syncthreads();
    #pragma unroll
    for (int kk = 0; kk < 2; kk++){
      const int kbyte = (kk*64 + (l >> 4)*16) ^ xorv;
      s16x8 af[4], bff[4];
      #pragma unroll
      for (int m = 0; m < 4; m++)
        af[m]  = *(const s16x8*)((const char*)As + (wr*64 + m*16 + (l & 15))*128 + kbyte);
      #pragma unroll
      for (int n = 0; n < 4; n++)
        bff[n] = *(const s16x8*)((const char*)Bs + (wc*64 + n*16 + (l & 15))*128 + kbyte);
      #pragma unroll
      for (int m = 0; m < 4; m++)
        #pragma unroll
        for (int n = 0; n < 4; n++)
          acc[m][n] = __builtin_amdgcn_mfma_f32_16x16x32_bf16(af[m], bff[n], acc[m][n], 0, 0, 0);
    }
    __syncthreads();
  }
  const int lc = l & 15, lr4 = (l >> 4)*4;
  OutT* Cz = Cmat + (size_t)blockIdx.z * sC;
  #pragma unroll
  for (int n = 0; n < 4; n++){
    const int col = n0 + wc*64 + n*16 + lc;
    float bv = 0.f;
    if (EPI & 8){
      const float* bp = (col < 512) ? b0 : (col < 1024 ? b1 : b2);
      bv = bp[col & 511];
    } else if (EPI & 1){
      bv = b0[col];
    }
    #pragma unroll
    for (int m = 0; m < 4; m++){
      const int rowb = m0 + wr*64 + m*16 + lr4;
      #pragma unroll
      for (int r = 0; r < 4; r++){
        float v = acc[m][n][r];
        if (EPI & 2) v *= scale;
        v += bv;
        const size_t off = (size_t)(rowb + r)*ldc + col;
        if (EPI & 4) v += res[off];
        if constexpr (__is_same(OutT, float)) Cz[off] = v;
        else ((u16*)Cz)[off] = f2b(v);
      }
    }
  }
}

// ---------------- 256x256 8-phase GEMM (T2+T3+T4+T5), BK=64, 8 waves ---------------
// L[buf][mat(A=0/B=1)][kstep][256 rows x 32 cols], 128 KB. Half-tile = (mat,kstep),
// 16 KB contiguous -> global_load_lds. Swizzle: byte-col ^= ((row>>1)&3)<<4.
// Schedule (iter i = K-tiles 2i,2i+1): ph1..8 compute (buf,kk,Mq) =
// (0,0,0)(0,0,1)(0,1,0)(0,1,1)(1,0,0)(1,0,1)(1,1,0)(1,1,1); stages:
// ph1:A1(2i+1) ph2:B1(2i+1) ph3:A0(2i+2) ph4:B0(2i+2)+vmcnt(4) ph5:A1(2i+2)
// ph6:B1(2i+2) ph7:A0(2i+3) ph8:B0(2i+3)+vmcnt(4). All regions freed 1+ phase
// before their stage; vmcnt(4) => compute data fully landed, 2 half-tiles in flight.
template<int EPI, typename OutT>
__global__ __launch_bounds__(512, 2) void gemm256(
    const u16* __restrict__ A, int lda, long sA,
    const u16* __restrict__ Bt, int ldb, long sB,
    OutT* __restrict__ Cmat, int ldc, long sC,
    int K, float scale,
    const float* __restrict__ b0, const float* __restrict__ b1,
    const float* __restrict__ b2, const float* __restrict__ res)
{
  __shared__ u16 L[2][2][2][256*32];
  const int t = threadIdx.x, l = t & 63, w = t >> 3 >> 3;  // w = t>>6
  const int wm = w >> 2, wn = w & 3;
  int bx = blockIdx.x, by = blockIdx.y;
  {
    const int gx = gridDim.x, nb = gx * gridDim.y;
    if ((nb & 7) == 0){
      int lin = by*gx + bx;
      int s = (lin & 7)*(nb >> 3) + (lin >> 3);
      bx = s % gx; by = s / gx;
    }
  }
  const int m0 = by * 256, n0 = bx * 256;
  const u16* Au  = A  + (size_t)blockIdx.z * sA;
  const u16* Btu = Bt + (size_t)blockIdx.z * sB;

  f32x4 acc[8][4];
  #pragma unroll
  for (int m = 0; m < 8; m++)
    #pragma unroll
    for (int n = 0; n < 4; n++) acc[m][n] = (f32x4){0.f,0.f,0.f,0.f};

  // staging constants: thread t covers LDS bytes t*16 (+8192) of a 16KB half
  const int srow_s = t >> 2;                           // row 0..127 (j=0), +128 (j=1)
  const int sce    = (((t & 3)*16) ^ (((srow_s >> 1) & 3) << 4)) >> 1;  // src col els
  const int l15 = l & 15, kb16 = (l >> 4)*16;

  // per-thread frag byte offsets (constant across phases)
  int arow[8], brow[4];
  #pragma unroll
  for (int i = 0; i < 8; i++){
    const int r = wm*128 + i*16 + l15;
    arow[i] = r*64 + (kb16 ^ (((r >> 1) & 3) << 4));
  }
  #pragma unroll
  for (int i = 0; i < 4; i++){
    const int r = wn*64 + i*16 + l15;
    brow[i] = r*64 + (kb16 ^ (((r >> 1) & 3) << 4));
  }

#define STG256(HALF, XU, LD, ROW0, COLBASE) do { \
    GLDS16((XU) + (size_t)((ROW0) + srow_s)*(LD) + (COLBASE) + sce, \
           (char*)(HALF) + w*1024); \
    GLDS16((XU) + (size_t)((ROW0) + 128 + srow_s)*(LD) + (COLBASE) + sce, \
           (char*)(HALF) + 8192 + w*1024); \
  } while(0)

#define VMW4 asm volatile("s_waitcnt vmcnt(4)" ::: "memory")

#define PH256(BUF, KK, MQ, STAGE_STMT, WAIT_STMT) do { \
    s16x8 af_[4], bg_[4]; \
    _Pragma("unroll") \
    for (int mf = 0; mf < 4; mf++) \
      af_[mf] = *(const s16x8*)((const char*)&L[BUF][0][KK][0] + arow[(MQ)*4 + mf]); \
    _Pragma("unroll") \
    for (int nf = 0; nf < 4; nf++) \
      bg_[nf] = *(const s16x8*)((const char*)&L[BUF][1][KK][0] + brow[nf]); \
    STAGE_STMT; \
    WAIT_STMT; \
    __builtin_amdgcn_s_barrier(); \
    __builtin_amdgcn_s_setprio(1); \
    _Pragma("unroll") \
    for (int mf = 0; mf < 4; mf++) \
      _Pragma("unroll") \
      for (int nf = 0; nf < 4; nf++) \
        acc[(MQ)*4 + mf][nf] = __builtin_amdgcn_mfma_f32_16x16x32_bf16( \
            af_[mf], bg_[nf], acc[(MQ)*4 + mf][nf], 0, 0, 0); \
    __builtin_amdgcn_s_setprio(0); \
    __builtin_amdgcn_s_barrier(); \
  } while(0)

  const int nkt = K >> 6;       // 64-wide K-tiles
  // prologue: K-tile0 all 4 halves -> buf0; K-tile1 A0,B0 -> buf1
  STG256(&L[0][0][0][0], Au,  lda, m0, 0);
  STG256(&L[0][1][0][0], Btu, ldb, n0, 0);
  STG256(&L[0][0][1][0], Au,  lda, m0, 32);
  STG256(&L[0][1][1][0], Btu, ldb, n0, 32);
  STG256(&L[1][0][0][0], Au,  lda, m0, 64);
  STG256(&L[1][1][0][0], Btu, ldb, n0, 64);
  VMW4;
  __builtin_amdgcn_s_barrier();

  const int niter = nkt >> 1;
  for (int it = 0; it < niter; ++it){
    const int kt1 = 2*it + 1;
    const int kA  = (kt1 + 1 < nkt) ? kt1 + 1 : nkt - 1;   // 2i+2 clamped
    const int kB  = (kt1 + 2 < nkt) ? kt1 + 2 : nkt - 1;   // 2i+3 clamped
    PH256(0, 0, 0, STG256(&L[1][0][1][0], Au,  lda, m0, kt1*64 + 32), (void)0);
    PH256(0, 0, 1, STG256(&L[1][1][1][0], Btu, ldb, n0, kt1*64 + 32), (void)0);
    PH256(0, 1, 0, STG256(&L[0][0][0][0], Au,  lda, m0, kA*64),       (void)0);
    PH256(0, 1, 1, STG256(&L[0][1][0][0], Btu, ldb, n0, kA*64),       VMW4);
    PH256(1, 0, 0, STG256(&L[0][0][1][0], Au,  lda, m0, kA*64 + 32),  (void)0);
    PH256(1, 0, 1, STG256(&L[0][1][1][0], Btu, ldb, n0, kA*64 + 32),  (void)0);
    PH256(1, 1, 0, STG256(&L[1][0][0][0], Au,  lda, m0, kB*64),       (void)0);
    PH256(1, 1, 1, STG256(&L[1][1][0][0], Btu, ldb, n0, kB*64),       VMW4);
  }

  // epilogue
  const int lc = l15, lr4 = (l >> 4)*4;
  OutT* Cz = Cmat + (size_t)blockIdx.z * sC;
  #pragma unroll
  for (int nf = 0; nf < 4; nf++){
    const int col = n0 + wn*64 + nf*16 + lc;
    float bv = 0.f;
    if (EPI & 8){
      const float* bp = (col < 512) ? b0 : (col < 1024 ? b1 : b2);
      bv = bp[col & 511];
    } else if (EPI & 1){
      bv = b0[col];
    }
    #pragma unroll
    for (int mf = 0; mf < 8; mf++){
      const int rowb = m0 + wm*128 + mf*16 + lr4;
      #pragma unroll
      for (int r = 0; r < 4; r++){
        float v = acc[mf][nf][r];
        if (EPI & 2) v *= scale;
        v += bv;
        const size_t off = (size_t)(rowb + r)*ldc + col;
        if (EPI & 4) v += res[off];
        if constexpr (__is_same(OutT, float)) Cz[off] = v;
        else ((u16*)Cz)[off] = f2b(v);
      }
    }
  }
#undef STG256
#undef VMW4
#undef PH256
}

// ---------------- Fused softmax + PV (fixed-reference, counted-vmcnt) --------------
__global__ __launch_bounds__(512) void pv_fused(
    const u16* __restrict__ S, const u16* __restrict__ vT,
    bf16* __restrict__ ao, int batched, int batch0)
{
  __shared__ u16 Bs[256*64];
  __shared__ u16 Ps[64*64];
  __shared__ float lsArr[64];
  const int t = threadIdx.x, l = t & 63, w = t >> 6;
  int batch, mt, half;
  if (batched){
    const int lin = blockIdx.x, x = lin & 7, s = lin >> 3;
    batch = x >> 1; mt = (s >> 1)*2 + (x & 1); half = s & 1;
  } else { batch = batch0; mt = blockIdx.x >> 1; half = blockIdx.x & 1; }
  const int m0 = mt*64, c0 = half*256;
  const u16* Sb  = S  + (size_t)batch*4096*4096;
  const u16* vTb = vT + (size_t)batch*512*4096 + (size_t)c0*4096;
  u16* aob = (u16*)ao + (size_t)batch*4096*512;

  f32x4 acc[4][2];
  #pragma unroll
  for (int m = 0; m < 4; m++)
    #pragma unroll
    for (int n = 0; n < 2; n++) acc[m][n] = (f32x4){0.f,0.f,0.f,0.f};

  const int srow = l >> 3, lane8 = l & 7;
  const int scol = (lane8 ^ srow) * 8;
  const int xorv = lane8 << 4;
  const int r_loc = w*8 + srow;
  const int smaddr = r_loc*128 + ((lane8*16) ^ (srow << 4));
  float lsumrow = 0.f;

  const u16* Srow = Sb + (size_t)(m0 + r_loc)*4096 + lane8*8;

  #pragma unroll
  for (int j = 0; j < 4; j++){
    const int chunk = w*4 + j;
    const int row = chunk*8 + srow;
    GLDS16(vTb + (size_t)row*4096 + scol, &Bs[chunk*512]);
  }
  s16x8 S_cur = *(const s16x8*)Srow;

  for (int kt = 0; kt < 64; ++kt){
    const int ktn = (kt < 63) ? kt + 1 : 63;
    s16x8 S_next = *(const s16x8*)(Srow + ktn*64);

    float rs = 0.f;
    s16x8 pb;
    #pragma unroll
    for (int j = 0; j < 8; j++){
      const float pvv = exp2f(fminf(b2f((u16)S_cur[j]), 100.f));
      rs += pvv;
      pb[j] = (short)f2b(pvv);
    }
    rs += __shfl_xor(rs, 1); rs += __shfl_xor(rs, 2); rs += __shfl_xor(rs, 4);
    lsumrow += rs;

    *(s16x8*)((char*)Ps + smaddr) = pb;

    asm volatile("s_waitcnt lgkmcnt(0)" ::: "memory");
    __builtin_amdgcn_sched_barrier(0);
    asm volatile("s_waitcnt vmcnt(1)" ::: "memory");
    __builtin_amdgcn_sched_barrier(0);
    __builtin_amdgcn_s_barrier();

    #pragma unroll
    for (int kk = 0; kk < 2; kk++){
      const int kbyte = (kk*64 + (l >> 4)*16) ^ xorv;
      s16x8 pa[4], bf2[2];
      #pragma unroll
      for (int m = 0; m < 4; m++)
        pa[m] = *(const s16x8*)((const char*)Ps + (m*16 + (l & 15))*128 + kbyte);
      #pragma unroll
      for (int n = 0; n < 2; n++)
        bf2[n] = *(const s16x8*)((const char*)Bs + (w*32 + n*16 + (l & 15))*128 + kbyte);
      #pragma unroll
      for (int m = 0; m < 4; m++)
        #pragma unroll
        for (int n = 0; n < 2; n++)
          acc[m][n] = __builtin_amdgcn_mfma_f32_16x16x32_bf16(pa[m], bf2[n], acc[m][n], 0, 0, 0);
    }

    __builtin_amdgcn_sched_barrier(0);
    __builtin_amdgcn_s_barrier();
    __builtin_amdgcn_sched_barrier(0);

    #pragma unroll
    for (int j = 0; j < 4; j++){
      const int chunk = w*4 + j;
      const int row = chunk*8 + srow;
      GLDS16(vTb + (size_t)row*4096 + ktn*64 + scol, &Bs[chunk*512]);
    }
    S_cur = S_next;
  }

  if (lane8 == 0) lsArr[r_loc] = lsumrow;
  __syncthreads();
  #pragma unroll
  for (int m = 0; m < 4; m++){
    const f32x4 lq = *(const f32x4*)&lsArr[m*16 + (l >> 4)*4];
    #pragma unroll
    for (int r = 0; r < 4; r++){
      const float inv = 1.f / lq[r];
      const int row = m0 + m*16 + (l >> 4)*4 + r;
      #pragma unroll
      for (int n = 0; n < 2; n++){
        const int col = c0 + w*32 + n*16 + (l & 15);
        aob[(size_t)row*512 + col] = f2b(acc[m][n][r] * inv);
      }
    }
  }
}

// -----------------------------------------------------------------------------------
extern "C" void kernel_launch(void* const* d_in, const int* in_sizes, int n_in,
                              void* d_out, int out_size, void* d_ws, size_t ws_size,
                              hipStream_t stream)
{
  (void)in_sizes; (void)n_in; (void)out_size;
  const float* x     = (const float*)d_in[0];
  const float* gamma = (const float*)d_in[1];
  const float* beta  = (const float*)d_in[2];
  const float* Wq = (const float*)d_in[3]; const float* bq = (const float*)d_in[4];
  const float* Wk = (const float*)d_in[5]; const float* bk = (const float*)d_in[6];
  const float* Wv = (const float*)d_in[7]; const float* bv = (const float*)d_in[8];
  const float* Wo = (const float*)d_in[9]; const float* bo = (const float*)d_in[10];
  float* out = (float*)d_out;

  const int B = 4, N = 4096, C = 512;
  const long NC = (long)N*C;
  const float scl2 = 0.04419417382415922f * 1.4426950408889634f;  // C^-.5 * log2(e)

  char* p0 = (char*)d_ws;
  auto align = [](size_t b){ return (b + 255) & ~(size_t)255; };
  const size_t sz_h   = align((size_t)B*NC*2);
  const size_t sz_w   = align((size_t)4*C*C*2);
  const size_t sz_qkvF= align((size_t)B*N*1536*2);
  const size_t sz_vTF = align((size_t)B*NC*2);
  const size_t sz_aoF = align((size_t)B*NC*2);
  const size_t sz_SF  = align((size_t)B*N*N*2);
  const size_t need_full = sz_h + sz_w + sz_qkvF + sz_vTF + sz_aoF + sz_SF;

  bf16* h    = (bf16*)p0;
  bf16* wAll = (bf16*)(p0 + sz_h);
  char* pv   = p0 + sz_h + sz_w;

  gn_kernel<<<dim3(B*32), dim3(512), 0, stream>>>(x, gamma, beta, h);
  W4 ws4; ws4.p[0] = Wq; ws4.p[1] = Wk; ws4.p[2] = Wv; ws4.p[3] = Wo;
  transpose_w4<<<dim3(8, 8, 4), 256, 0, stream>>>(ws4, wAll);
  bf16* woT = wAll + (size_t)3*C*C;

  if (ws_size >= need_full){
    bf16* qkv = (bf16*)pv;
    bf16* vT  = (bf16*)(pv + sz_qkvF);
    bf16* ao  = (bf16*)(pv + sz_qkvF + sz_vTF);
    bf16* S   = (bf16*)(pv + sz_qkvF + sz_vTF + sz_aoF);

    gemm256<8, bf16><<<dim3(6, 64, 1), 512, 0, stream>>>(
        (const u16*)h, C, 0, (const u16*)wAll, C, 0, qkv, 1536, 0,
        C, 1.f, bq, bk, bv, nullptr);
    transpose_v<<<dim3(8, 64, B), 256, 0, stream>>>((const u16*)qkv, vT);
    gemm256<2, bf16><<<dim3(16, 16, B), 512, 0, stream>>>(
        (const u16*)qkv, 1536, (long)N*1536, (const u16*)qkv + 512, 1536, (long)N*1536,
        S, N, (long)N*N, C, scl2, nullptr, nullptr, nullptr, nullptr);
    pv_fused<<<dim3(512), 512, 0, stream>>>(
        (const u16*)S, (const u16*)vT, ao, 1, 0);
    gemm_bt<5, float><<<dim3(4, 128, 1), 256, 0, stream>>>(
        (const u16*)ao, C, 0, (const u16*)woT, C, 0, out, C, 0,
        C, 1.f, bo, nullptr, nullptr, x);
  } else {
    const size_t sz_qkv1 = align((size_t)N*1536*2);
    const size_t sz_vT1  = align((size_t)NC*2);
    const size_t sz_ao1  = align((size_t)NC*2);
    bf16* qkv = (bf16*)pv;
    bf16* vT  = (bf16*)(pv + sz_qkv1);
    bf16* ao  = (bf16*)(pv + sz_qkv1 + sz_vT1);
    bf16* S   = (bf16*)(pv + sz_qkv1 + sz_vT1 + sz_ao1);
    for (int b = 0; b < B; b++){
      const u16* hb = (const u16*)h + (size_t)b*NC;
      gemm256<8, bf16><<<dim3(6, 16, 1), 512, 0, stream>>>(
          hb, C, 0, (const u16*)wAll, C, 0, qkv, 1536, 0,
          C, 1.f, bq, bk, bv, nullptr);
      transpose_v<<<dim3(8, 64, 1), 256, 0, stream>>>((const u16*)qkv, vT);
      gemm256<2, bf16><<<dim3(16, 16, 1), 512, 0, stream>>>(
          (const u16*)qkv, 1536, 0, (const u16*)qkv + 512, 1536, 0,
          S, N, 0, C, scl2, nullptr, nullptr, nullptr, nullptr);
      pv_fused<<<dim3(128), 512, 0, stream>>>(
          (const u16*)S, (const u16*)vT, ao, 0, b);
      gemm_bt<5, float><<<dim3(4, 32, 1), 256, 0, stream>>>(
          (const u16*)ao, C, 0, (const u16*)woT, C, 0, out + (size_t)b*NC, C, 0,
          C, 1.f, bo, nullptr, nullptr, x + (size_t)b*NC);
    }
  }
}

// Round 9
// 401.559 us; speedup vs baseline: 1.0573x; 1.0573x over previous
//
#include <hip/hip_runtime.h>
#include <hip/hip_bf16.h>

using bf16 = __hip_bfloat16;
using u16  = unsigned short;
typedef __attribute__((ext_vector_type(8))) short s16x8;
typedef __attribute__((ext_vector_type(4))) float f32x4;

__device__ __forceinline__ float b2f(u16 u){
  union{unsigned u; float f;} c; c.u = ((unsigned)u)<<16; return c.f;
}
__device__ __forceinline__ u16 f2b(float f){
  __hip_bfloat16 h = __float2bfloat16(f);
  return *reinterpret_cast<u16*>(&h);
}

#define GLDS16(g, l_) __builtin_amdgcn_global_load_lds( \
    (const __attribute__((address_space(1))) unsigned int*)(g), \
    (__attribute__((address_space(3))) unsigned int*)(l_), 16, 0, 0)

// ---------------- GroupNorm: x[4,4096,512] fp32 -> h bf16, 32 groups of 16 ch ------
__global__ __launch_bounds__(512) void gn_kernel(const float* __restrict__ x,
    const float* __restrict__ gamma, const float* __restrict__ beta,
    bf16* __restrict__ h)
{
  const int b = blockIdx.x >> 5, g = blockIdx.x & 31;
  const int t = threadIdx.x;
  const size_t base = (size_t)b*4096*512 + (size_t)g*16;
  float sum = 0.f, sq = 0.f;
  for (int i = 0; i < 8; i++){
    const float* p = x + base + (size_t)(i*512 + t)*512;
    #pragma unroll
    for (int j = 0; j < 4; j++){
      f32x4 v = *(const f32x4*)(p + j*4);
      #pragma unroll
      for (int e = 0; e < 4; e++){ sum += v[e]; sq += v[e]*v[e]; }
    }
  }
  __shared__ float red[16];
  for (int o = 32; o > 0; o >>= 1){ sum += __shfl_xor(sum, o); sq += __shfl_xor(sq, o); }
  const int w = t >> 6, l = t & 63;
  if (l == 0){ red[w] = sum; red[8 + w] = sq; }
  __syncthreads();
  if (t == 0){
    float a = 0.f, bb = 0.f;
    for (int i = 0; i < 8; i++){ a += red[i]; bb += red[8 + i]; }
    red[0] = a; red[8] = bb;
  }
  __syncthreads();
  const float inv_n = 1.f/65536.f;
  const float mean = red[0]*inv_n;
  const float var  = red[8]*inv_n - mean*mean;
  const float rstd = rsqrtf(var + 1e-6f);
  float ga[16], be[16];
  #pragma unroll
  for (int j = 0; j < 16; j++){
    ga[j] = gamma[g*16 + j];
    be[j] = beta [g*16 + j];
  }
  u16* hp = (u16*)h;
  for (int i = 0; i < 8; i++){
    const float* p = x + base + (size_t)(i*512 + t)*512;
    u16* q = hp + base + (size_t)(i*512 + t)*512;
    s16x8 o0, o1;
    #pragma unroll
    for (int j = 0; j < 4; j++){
      f32x4 v = *(const f32x4*)(p + j*4);
      #pragma unroll
      for (int e = 0; e < 4; e++){
        int c = j*4 + e;
        u16 r = f2b((v[e] - mean)*rstd*ga[c] + be[c]);
        if (c < 8) o0[c] = (short)r; else o1[c - 8] = (short)r;
      }
    }
    *(s16x8*)q = o0; *(s16x8*)(q + 8) = o1;
  }
}

// ---------------- Weight transpose: 4x [512,512] fp32 -> bf16 transposed -----------
struct W4 { const float* p[4]; };
__global__ __launch_bounds__(256) void transpose_w4(W4 srcs, bf16* __restrict__ dst)
{
  __shared__ float tile[64][65];
  const float* in = srcs.p[blockIdx.z];
  u16* out = (u16*)dst + (size_t)blockIdx.z*512*512;
  const int tr = blockIdx.y*64, tc = blockIdx.x*64;
  const int t = threadIdx.x;
  #pragma unroll
  for (int i = 0; i < 16; i++){
    int idx = i*256 + t, r = idx >> 6, c = idx & 63;
    tile[r][c] = in[(size_t)(tr + r)*512 + tc + c];
  }
  __syncthreads();
  #pragma unroll
  for (int i = 0; i < 16; i++){
    int idx = i*256 + t, r = idx >> 6, c = idx & 63;
    out[(size_t)(tc + r)*512 + tr + c] = f2b(tile[c][r]);
  }
}

// ---------------- 128x128 GEMM (BT form), used for out-proj ------------------------
// EPI bits: 1 = +b0[col], 2 = *scale, 4 = +res[row*ldc+col] (fp32).
template<int EPI, typename OutT>
__global__ __launch_bounds__(256) void gemm_bt(
    const u16* __restrict__ A, int lda, long sA,
    const u16* __restrict__ Bt, int ldb, long sB,
    OutT* __restrict__ Cmat, int ldc, long sC,
    int K, float scale,
    const float* __restrict__ b0, const float* __restrict__ res)
{
  __shared__ u16 As[128*64];
  __shared__ u16 Bs[128*64];
  const int t = threadIdx.x, l = t & 63, w = t >> 6;
  const int wr = w >> 1, wc = w & 1;
  int bx = blockIdx.x, by = blockIdx.y;
  {
    const int gx = gridDim.x, nb = gx * gridDim.y;
    if ((nb & 7) == 0){
      int lin = by*gx + bx;
      int s = (lin & 7)*(nb >> 3) + (lin >> 3);
      bx = s % gx; by = s / gx;
    }
  }
  const int m0 = by * 128, n0 = bx * 128;
  const u16* Au  = A  + (size_t)blockIdx.z * sA;
  const u16* Btu = Bt + (size_t)blockIdx.z * sB;

  f32x4 acc[4][4];
  #pragma unroll
  for (int m = 0; m < 4; m++)
    #pragma unroll
    for (int n = 0; n < 4; n++) acc[m][n] = (f32x4){0.f,0.f,0.f,0.f};

  const int srow = l >> 3;
  const int scol = ((l & 7) ^ srow) * 8;
  const int xorv = (l & 7) << 4;
  const int nkt = K >> 6;
  for (int kt = 0; kt < nkt; ++kt){
    const int k0 = kt << 6;
    #pragma unroll
    for (int j = 0; j < 4; j++){
      const int chunk = w*4 + j;
      const int row = chunk*8 + srow;
      GLDS16(Au  + (size_t)(m0 + row)*lda + k0 + scol, &As[chunk*512]);
      GLDS16(Btu + (size_t)(n0 + row)*ldb + k0 + scol, &Bs[chunk*512]);
    }
    __syncthreads();
    #pragma unroll
    for (int kk = 0; kk < 2; kk++){
      const int kbyte = (kk*64 + (l >> 4)*16) ^ xorv;
      s16x8 af[4], bff[4];
      #pragma unroll
      for (int m = 0; m < 4; m++)
        af[m]  = *(const s16x8*)((const char*)As + (wr*64 + m*16 + (l & 15))*128 + kbyte);
      #pragma unroll
      for (int n = 0; n < 4; n++)
        bff[n] = *(const s16x8*)((const char*)Bs + (wc*64 + n*16 + (l & 15))*128 + kbyte);
      #pragma unroll
      for (int m = 0; m < 4; m++)
        #pragma unroll
        for (int n = 0; n < 4; n++)
          acc[m][n] = __builtin_amdgcn_mfma_f32_16x16x32_bf16(af[m], bff[n], acc[m][n], 0, 0, 0);
    }
    __syncthreads();
  }
  const int lc = l & 15, lr4 = (l >> 4)*4;
  OutT* Cz = Cmat + (size_t)blockIdx.z * sC;
  #pragma unroll
  for (int n = 0; n < 4; n++){
    const int col = n0 + wc*64 + n*16 + lc;
    const float bv = (EPI & 1) ? b0[col] : 0.f;
    #pragma unroll
    for (int m = 0; m < 4; m++){
      const int rowb = m0 + wr*64 + m*16 + lr4;
      #pragma unroll
      for (int r = 0; r < 4; r++){
        float v = acc[m][n][r];
        if (EPI & 2) v *= scale;
        v += bv;
        const size_t off = (size_t)(rowb + r)*ldc + col;
        if (EPI & 4) v += res[off];
        if constexpr (__is_same(OutT, float)) Cz[off] = v;
        else ((u16*)Cz)[off] = f2b(v);
      }
    }
  }
}

// ---------------- 256x256 8-phase GEMM (T2+T3+T4+T5) + LDS-bounce epilogue ---------
// OMODE 0: dense bf16 store to C0 (ldc, sC). OMODE 1: split-QKV — col-blocks
// [0,512)->C0 (q dense ld512), [512,1024)->C1 (k dense), [1024,1536)->C2 = vT
// (transposed store, batch = m0>>12). EPI: 1=+b0[col], 2=*scale, 8=3-way bias.
template<int EPI, int OMODE>
__global__ __launch_bounds__(512, 2) void gemm256(
    const u16* __restrict__ A, int lda, long sA,
    const u16* __restrict__ Bt, int ldb, long sB,
    u16* __restrict__ C0, int ldc, long sC,
    u16* __restrict__ C1, u16* __restrict__ C2,
    int K, float scale,
    const float* __restrict__ b0, const float* __restrict__ b1,
    const float* __restrict__ b2)
{
  __shared__ u16 L[2][2][2][256*32];
  const int t = threadIdx.x, l = t & 63, w = t >> 6;
  const int wm = w >> 2, wn = w & 3;
  int bx = blockIdx.x, by = blockIdx.y;
  {
    const int gx = gridDim.x, nb = gx * gridDim.y;
    if ((nb & 7) == 0){
      int lin = by*gx + bx;
      int s = (lin & 7)*(nb >> 3) + (lin >> 3);
      bx = s % gx; by = s / gx;
    }
  }
  const int m0 = by * 256, n0 = bx * 256;
  const u16* Au  = A  + (size_t)blockIdx.z * sA;
  const u16* Btu = Bt + (size_t)blockIdx.z * sB;

  f32x4 acc[8][4];
  #pragma unroll
  for (int m = 0; m < 8; m++)
    #pragma unroll
    for (int n = 0; n < 4; n++) acc[m][n] = (f32x4){0.f,0.f,0.f,0.f};

  const int srow_s = t >> 2;
  const int sce    = (((t & 3)*16) ^ (((srow_s >> 1) & 3) << 4)) >> 1;
  const int l15 = l & 15, kb16 = (l >> 4)*16;

  int arow[8], brow[4];
  #pragma unroll
  for (int i = 0; i < 8; i++){
    const int r = wm*128 + i*16 + l15;
    arow[i] = r*64 + (kb16 ^ (((r >> 1) & 3) << 4));
  }
  #pragma unroll
  for (int i = 0; i < 4; i++){
    const int r = wn*64 + i*16 + l15;
    brow[i] = r*64 + (kb16 ^ (((r >> 1) & 3) << 4));
  }

#define STG256(HALF, XU, LD, ROW0, COLBASE) do { \
    GLDS16((XU) + (size_t)((ROW0) + srow_s)*(LD) + (COLBASE) + sce, \
           (char*)(HALF) + w*1024); \
    GLDS16((XU) + (size_t)((ROW0) + 128 + srow_s)*(LD) + (COLBASE) + sce, \
           (char*)(HALF) + 8192 + w*1024); \
  } while(0)

#define VMW4 asm volatile("s_waitcnt vmcnt(4)" ::: "memory")

#define PH256(BUF, KK, MQ, STAGE_STMT, WAIT_STMT) do { \
    s16x8 af_[4], bg_[4]; \
    _Pragma("unroll") \
    for (int mf = 0; mf < 4; mf++) \
      af_[mf] = *(const s16x8*)((const char*)&L[BUF][0][KK][0] + arow[(MQ)*4 + mf]); \
    _Pragma("unroll") \
    for (int nf = 0; nf < 4; nf++) \
      bg_[nf] = *(const s16x8*)((const char*)&L[BUF][1][KK][0] + brow[nf]); \
    STAGE_STMT; \
    WAIT_STMT; \
    __builtin_amdgcn_s_barrier(); \
    __builtin_amdgcn_s_setprio(1); \
    _Pragma("unroll") \
    for (int mf = 0; mf < 4; mf++) \
      _Pragma("unroll") \
      for (int nf = 0; nf < 4; nf++) \
        acc[(MQ)*4 + mf][nf] = __builtin_amdgcn_mfma_f32_16x16x32_bf16( \
            af_[mf], bg_[nf], acc[(MQ)*4 + mf][nf], 0, 0, 0); \
    __builtin_amdgcn_s_setprio(0); \
    __builtin_amdgcn_s_barrier(); \
  } while(0)

  const int nkt = K >> 6;
  STG256(&L[0][0][0][0], Au,  lda, m0, 0);
  STG256(&L[0][1][0][0], Btu, ldb, n0, 0);
  STG256(&L[0][0][1][0], Au,  lda, m0, 32);
  STG256(&L[0][1][1][0], Btu, ldb, n0, 32);
  STG256(&L[1][0][0][0], Au,  lda, m0, 64);
  STG256(&L[1][1][0][0], Btu, ldb, n0, 64);
  VMW4;
  __builtin_amdgcn_s_barrier();

  const int niter = nkt >> 1;
  for (int it = 0; it < niter; ++it){
    const int kt1 = 2*it + 1;
    const int kA  = (kt1 + 1 < nkt) ? kt1 + 1 : nkt - 1;
    const int kB  = (kt1 + 2 < nkt) ? kt1 + 2 : nkt - 1;
    PH256(0, 0, 0, STG256(&L[1][0][1][0], Au,  lda, m0, kt1*64 + 32), (void)0);
    PH256(0, 0, 1, STG256(&L[1][1][1][0], Btu, ldb, n0, kt1*64 + 32), (void)0);
    PH256(0, 1, 0, STG256(&L[0][0][0][0], Au,  lda, m0, kA*64),       (void)0);
    PH256(0, 1, 1, STG256(&L[0][1][0][0], Btu, ldb, n0, kA*64),       VMW4);
    PH256(1, 0, 0, STG256(&L[0][0][1][0], Au,  lda, m0, kA*64 + 32),  (void)0);
    PH256(1, 0, 1, STG256(&L[0][1][1][0], Btu, ldb, n0, kA*64 + 32),  (void)0);
    PH256(1, 1, 0, STG256(&L[1][0][0][0], Au,  lda, m0, kB*64),       (void)0);
    PH256(1, 1, 1, STG256(&L[1][1][0][0], Btu, ldb, n0, kB*64),       VMW4);
  }

  // ---- epilogue: drain stages, bounce acc -> LDS (swizzled), coalesced stores ----
  asm volatile("s_waitcnt vmcnt(0)" ::: "memory");
  __builtin_amdgcn_s_barrier();
  u16* Lb = (u16*)&L[0][0][0][0];           // reused as 256x256 bf16 tile
  const int lr4 = (l >> 4)*4;
  #pragma unroll
  for (int nf = 0; nf < 4; nf++){
    const int cloc = wn*64 + nf*16 + l15;
    const int colg = n0 + cloc;
    float bv = 0.f;
    if (EPI & 8){
      const float* bp = (colg < 512) ? b0 : (colg < 1024 ? b1 : b2);
      bv = bp[colg & 511];
    } else if (EPI & 1) bv = b0[colg];
    #pragma unroll
    for (int mf = 0; mf < 8; mf++){
      const int rl0 = wm*128 + mf*16 + lr4;
      #pragma unroll
      for (int r = 0; r < 4; r++){
        float v = acc[mf][nf][r];
        if (EPI & 2) v *= scale;
        v += bv;
        const int row = rl0 + r;
        const int byte = row*512 + ((cloc*2) ^ (((row >> 3) & 7) << 4));
        *(u16*)((char*)Lb + byte) = f2b(v);
      }
    }
  }
  __syncthreads();
  if (OMODE == 0){
    u16* Cz = C0 + (size_t)blockIdx.z * sC;
    #pragma unroll
    for (int i = 0; i < 16; i++){
      const int idx = i*512 + t;
      const int row = idx >> 5, cb = (idx & 31)*16;
      const int byte = row*512 + (cb ^ (((row >> 3) & 7) << 4));
      s16x8 v = *(const s16x8*)((const char*)Lb + byte);
      *(s16x8*)(Cz + (size_t)(m0 + row)*ldc + n0 + (cb >> 1)) = v;
    }
  } else {
    const int sec = n0 >> 9, wc0 = n0 & 511;
    if (sec < 2){
      u16* dst = (sec == 0) ? C0 : C1;
      #pragma unroll
      for (int i = 0; i < 16; i++){
        const int idx = i*512 + t;
        const int row = idx >> 5, cb = (idx & 31)*16;
        const int byte = row*512 + (cb ^ (((row >> 3) & 7) << 4));
        s16x8 v = *(const s16x8*)((const char*)Lb + byte);
        *(s16x8*)(dst + (size_t)(m0 + row)*512 + wc0 + (cb >> 1)) = v;
      }
    } else {
      // v section -> vT[batch][512][4096] (transposed store)
      const int batch = m0 >> 12, ntok = m0 & 4095;
      u16* dst = C2 + (size_t)batch*512*4096;
      #pragma unroll
      for (int i = 0; i < 16; i++){
        const int idx = i*512 + t;
        const int c_loc = idx >> 5, rseg = (idx & 31)*8;
        s16x8 v;
        #pragma unroll
        for (int j = 0; j < 8; j++){
          const int row = rseg + j;
          const int byte = row*512 + ((c_loc*2) ^ (((row >> 3) & 7) << 4));
          v[j] = *(const short*)((const char*)Lb + byte);
        }
        *(s16x8*)(dst + (size_t)(wc0 + c_loc)*4096 + ntok + rseg) = v;
      }
    }
  }
#undef STG256
#undef VMW4
#undef PH256
}

// ---------------- Fused softmax + PV (fixed-reference, counted-vmcnt) --------------
__global__ __launch_bounds__(512) void pv_fused(
    const u16* __restrict__ S, const u16* __restrict__ vT,
    bf16* __restrict__ ao, int batched, int batch0)
{
  __shared__ u16 Bs[256*64];
  __shared__ u16 Ps[64*64];
  __shared__ float lsArr[64];
  const int t = threadIdx.x, l = t & 63, w = t >> 6;
  int batch, mt, half;
  if (batched){
    const int lin = blockIdx.x, x = lin & 7, s = lin >> 3;
    batch = x >> 1; mt = (s >> 1)*2 + (x & 1); half = s & 1;
  } else { batch = batch0; mt = blockIdx.x >> 1; half = blockIdx.x & 1; }
  const int m0 = mt*64, c0 = half*256;
  const u16* Sb  = S  + (size_t)batch*4096*4096;
  const u16* vTb = vT + (size_t)batch*512*4096 + (size_t)c0*4096;
  u16* aob = (u16*)ao + (size_t)batch*4096*512;

  f32x4 acc[4][2];
  #pragma unroll
  for (int m = 0; m < 4; m++)
    #pragma unroll
    for (int n = 0; n < 2; n++) acc[m][n] = (f32x4){0.f,0.f,0.f,0.f};

  const int srow = l >> 3, lane8 = l & 7;
  const int scol = (lane8 ^ srow) * 8;
  const int xorv = lane8 << 4;
  const int r_loc = w*8 + srow;
  const int smaddr = r_loc*128 + ((lane8*16) ^ (srow << 4));
  float lsumrow = 0.f;          // per-lane partial; cross-lane reduce once at end

  const u16* Srow = Sb + (size_t)(m0 + r_loc)*4096 + lane8*8;

  #pragma unroll
  for (int j = 0; j < 4; j++){
    const int chunk = w*4 + j;
    const int row = chunk*8 + srow;
    GLDS16(vTb + (size_t)row*4096 + scol, &Bs[chunk*512]);
  }
  s16x8 S_cur = *(const s16x8*)Srow;

  for (int kt = 0; kt < 64; ++kt){
    const int ktn = (kt < 63) ? kt + 1 : 63;
    s16x8 S_next = *(const s16x8*)(Srow + ktn*64);

    s16x8 pb;
    #pragma unroll
    for (int j = 0; j < 8; j++){
      const float pvv = exp2f(fminf(b2f((u16)S_cur[j]), 100.f));
      lsumrow += pvv;
      pb[j] = (short)f2b(pvv);
    }

    *(s16x8*)((char*)Ps + smaddr) = pb;

    asm volatile("s_waitcnt lgkmcnt(0)" ::: "memory");
    __builtin_amdgcn_sched_barrier(0);
    asm volatile("s_waitcnt vmcnt(1)" ::: "memory");
    __builtin_amdgcn_sched_barrier(0);
    __builtin_amdgcn_s_barrier();

    #pragma unroll
    for (int kk = 0; kk < 2; kk++){
      const int kbyte = (kk*64 + (l >> 4)*16) ^ xorv;
      s16x8 pa[4], bf2[2];
      #pragma unroll
      for (int m = 0; m < 4; m++)
        pa[m] = *(const s16x8*)((const char*)Ps + (m*16 + (l & 15))*128 + kbyte);
      #pragma unroll
      for (int n = 0; n < 2; n++)
        bf2[n] = *(const s16x8*)((const char*)Bs + (w*32 + n*16 + (l & 15))*128 + kbyte);
      #pragma unroll
      for (int m = 0; m < 4; m++)
        #pragma unroll
        for (int n = 0; n < 2; n++)
          acc[m][n] = __builtin_amdgcn_mfma_f32_16x16x32_bf16(pa[m], bf2[n], acc[m][n], 0, 0, 0);
    }

    __builtin_amdgcn_sched_barrier(0);
    __builtin_amdgcn_s_barrier();
    __builtin_amdgcn_sched_barrier(0);

    #pragma unroll
    for (int j = 0; j < 4; j++){
      const int chunk = w*4 + j;
      const int row = chunk*8 + srow;
      GLDS16(vTb + (size_t)row*4096 + ktn*64 + scol, &Bs[chunk*512]);
    }
    S_cur = S_next;
  }

  // cross-lane row-sum reduce (once)
  lsumrow += __shfl_xor(lsumrow, 1);
  lsumrow += __shfl_xor(lsumrow, 2);
  lsumrow += __shfl_xor(lsumrow, 4);
  if (lane8 == 0) lsArr[r_loc] = lsumrow;
  __syncthreads();
  #pragma unroll
  for (int m = 0; m < 4; m++){
    const f32x4 lq = *(const f32x4*)&lsArr[m*16 + (l >> 4)*4];
    #pragma unroll
    for (int r = 0; r < 4; r++){
      const float inv = 1.f / lq[r];
      const int row = m0 + m*16 + (l >> 4)*4 + r;
      #pragma unroll
      for (int n = 0; n < 2; n++){
        const int col = c0 + w*32 + n*16 + (l & 15);
        aob[(size_t)row*512 + col] = f2b(acc[m][n][r] * inv);
      }
    }
  }
}

// -----------------------------------------------------------------------------------
extern "C" void kernel_launch(void* const* d_in, const int* in_sizes, int n_in,
                              void* d_out, int out_size, void* d_ws, size_t ws_size,
                              hipStream_t stream)
{
  (void)in_sizes; (void)n_in; (void)out_size;
  const float* x     = (const float*)d_in[0];
  const float* gamma = (const float*)d_in[1];
  const float* beta  = (const float*)d_in[2];
  const float* Wq = (const float*)d_in[3]; const float* bq = (const float*)d_in[4];
  const float* Wk = (const float*)d_in[5]; const float* bk = (const float*)d_in[6];
  const float* Wv = (const float*)d_in[7]; const float* bv = (const float*)d_in[8];
  const float* Wo = (const float*)d_in[9]; const float* bo = (const float*)d_in[10];
  float* out = (float*)d_out;

  const int B = 4, N = 4096, C = 512;
  const long NC = (long)N*C;
  const float scl2 = 0.04419417382415922f * 1.4426950408889634f;  // C^-.5 * log2(e)

  char* p0 = (char*)d_ws;
  auto align = [](size_t b){ return (b + 255) & ~(size_t)255; };
  const size_t sz_h  = align((size_t)B*NC*2);
  const size_t sz_w  = align((size_t)4*C*C*2);
  const size_t sz_q  = align((size_t)B*NC*2);
  const size_t sz_S  = align((size_t)B*N*N*2);
  const size_t need_full = sz_h + sz_w + 4*sz_q + sz_S;

  bf16* h    = (bf16*)p0;
  bf16* wAll = (bf16*)(p0 + sz_h);
  char* pv   = p0 + sz_h + sz_w;
  bf16* woT  = wAll + (size_t)3*C*C;

  gn_kernel<<<dim3(B*32), dim3(512), 0, stream>>>(x, gamma, beta, h);
  W4 ws4; ws4.p[0] = Wq; ws4.p[1] = Wk; ws4.p[2] = Wv; ws4.p[3] = Wo;
  transpose_w4<<<dim3(8, 8, 4), 256, 0, stream>>>(ws4, wAll);

  if (ws_size >= need_full){
    u16* q  = (u16*)pv;
    u16* k  = (u16*)(pv + sz_q);
    u16* vT = (u16*)(pv + 2*sz_q);
    u16* ao = (u16*)(pv + 3*sz_q);
    u16* S  = (u16*)(pv + 4*sz_q);

    gemm256<8, 1><<<dim3(6, 64, 1), 512, 0, stream>>>(
        (const u16*)h, C, 0, (const u16*)wAll, C, 0,
        q, 0, 0, k, vT, C, 1.f, bq, bk, bv);
    gemm256<2, 0><<<dim3(16, 16, B), 512, 0, stream>>>(
        q, C, NC, k, C, NC, S, N, (long)N*N, nullptr, nullptr,
        C, scl2, nullptr, nullptr, nullptr);
    pv_fused<<<dim3(512), 512, 0, stream>>>(
        S, vT, (bf16*)ao, 1, 0);
    gemm_bt<5, float><<<dim3(4, 128, 1), 256, 0, stream>>>(
        ao, C, 0, (const u16*)woT, C, 0, out, C, 0,
        C, 1.f, bo, x);
  } else {
    // per-batch fallback
    u16* q  = (u16*)pv;
    u16* k  = (u16*)(pv + sz_q/4 + 256);
    u16* vT = (u16*)(pv + 2*(sz_q/4 + 256));
    u16* ao = (u16*)(pv + 3*(sz_q/4 + 256));
    u16* S  = (u16*)(pv + 4*(sz_q/4 + 256));
    for (int b = 0; b < B; b++){
      const u16* hb = (const u16*)h + (size_t)b*NC;
      gemm256<8, 1><<<dim3(6, 16, 1), 512, 0, stream>>>(
          hb, C, 0, (const u16*)wAll, C, 0,
          q, 0, 0, k, vT, C, 1.f, bq, bk, bv);
      gemm256<2, 0><<<dim3(16, 16, 1), 512, 0, stream>>>(
          q, C, 0, k, C, 0, S, N, 0, nullptr, nullptr,
          C, scl2, nullptr, nullptr, nullptr);
      pv_fused<<<dim3(128), 512, 0, stream>>>(
          S, vT, (bf16*)ao, 0, 0);
      gemm_bt<5, float><<<dim3(4, 32, 1), 256, 0, stream>>>(
          ao, C, 0, (const u16*)woT, C, 0, out + (size_t)b*NC, C, 0,
          C, 1.f, bo, x + (size_t)b*NC);
    }
  }
}